// Round 2
// baseline (1059.078 us; speedup 1.0000x reference)
//
#include <hip/hip_runtime.h>
#include <hip/hip_bf16.h>
#include <stdint.h>

using bf16 = __hip_bfloat16;
typedef __attribute__((ext_vector_type(8))) short short8;
typedef __attribute__((ext_vector_type(4))) float f32x4;
typedef __attribute__((address_space(3))) unsigned int lds_u32;
typedef const __attribute__((address_space(1))) unsigned int gbl_u32;

#define HSTRIDE 1040
#define NNODES 1025
#define EE 16384
#define MAXDEG 192

__device__ __forceinline__ bf16 f2b(float x) { return __float2bfloat16(x); }
__device__ __forceinline__ float b2f(bf16 x) { return __bfloat162float(x); }

// ------------------------------------------- transpose f32 -> bf16 [C][R]
__global__ __launch_bounds__(256) void k_transpose_cvt(const float* __restrict__ in,
                                                       bf16* __restrict__ out, int R, int C) {
    __shared__ float tile[32][33];
    int bx = blockIdx.x * 32;  // c base
    int by = blockIdx.y * 32;  // r base
    int tx = threadIdx.x, ty = threadIdx.y;  // (32,8)
    for (int i = 0; i < 32; i += 8)
        tile[ty + i][tx] = in[(size_t)(by + ty + i) * C + bx + tx];
    __syncthreads();
    for (int i = 0; i < 32; i += 8)
        out[(size_t)(bx + ty + i) * R + by + tx] = f2b(tile[tx][ty + i]);
}

// ------------------------------------------------- small GEMM (N fixed 256)
__global__ __launch_bounds__(256) void k_small_mm(const float* __restrict__ X,
                                                  const float* __restrict__ W,
                                                  float* __restrict__ out, int Kdim) {
    int r = blockIdx.x, c = threadIdx.x;
    float acc = 0.f;
    for (int k = 0; k < Kdim; k++) acc += X[r * Kdim + k] * W[k * 256 + c];
    out[r * 256 + c] = acc;
}

// ---------------------------------------------------- classifier weight fold
// weff[c][k] = sum_e cls_w[k][e] * cls2_w[c][e]   (k<1280, c<50)
__global__ __launch_bounds__(256) void k_weff(const float* __restrict__ cls_w,
                                              const float* __restrict__ cls2_w,
                                              float* __restrict__ weff) {
    int c = blockIdx.y;
    int wave = threadIdx.x >> 6, lane = threadIdx.x & 63;
    int k = blockIdx.x * 4 + wave;
    float acc = 0.f;
    for (int e = lane; e < 768; e += 64)
        acc += cls_w[(size_t)k * 768 + e] * cls2_w[c * 768 + e];
    for (int s = 32; s > 0; s >>= 1) acc += __shfl_xor(acc, s, 64);
    if (lane == 0) weff[c * 1280 + k] = acc;
}

__global__ __launch_bounds__(64) void k_beff(const float* __restrict__ cls_b,
                                             const float* __restrict__ cls2_b,
                                             const float* __restrict__ cls2_w,
                                             float* __restrict__ beff) {
    int c = blockIdx.x, lane = threadIdx.x;
    float acc = 0.f;
    for (int e = lane; e < 768; e += 64) acc += cls_b[e] * cls2_w[c * 768 + e];
    for (int s = 32; s > 0; s >>= 1) acc += __shfl_xor(acc, s, 64);
    if (lane == 0) beff[c] = acc + cls2_b[c];
}

// ---------------------------------------------------------------- text_vec
__global__ __launch_bounds__(256) void k_textvec(const int* __restrict__ sent,
                                                 const float* __restrict__ mask,
                                                 const float* __restrict__ we,
                                                 float* __restrict__ tv) {
    int b = blockIdx.x, tid = threadIdx.x;
    __shared__ float red[256];
    red[tid] = mask[b * 256 + tid];
    __syncthreads();
    for (int s = 128; s > 0; s >>= 1) {
        if (tid < s) red[tid] += red[tid + s];
        __syncthreads();
    }
    float inv = 1.f / (red[0] + 1e-9f);
    float a0 = 0.f, a1 = 0.f, a2 = 0.f;
    for (int l = 0; l < 256; l++) {
        int w = sent[b * 256 + l];
        float mm = mask[b * 256 + l];
        const float* row = we + (size_t)w * 768;
        a0 += mm * row[tid];
        a1 += mm * row[tid + 256];
        a2 += mm * row[tid + 512];
    }
    tv[b * 768 + tid] = a0 * inv;
    tv[b * 768 + tid + 256] = a1 * inv;
    tv[b * 768 + tid + 512] = a2 * inv;
}

// ------------------------------- gather logic-node entity rows, f32 -> bf16
// gA[(b*512+np)*8+m][d] = entity[nodes[b][512+np][m]][d]
__global__ __launch_bounds__(256) void k_gath(const int* __restrict__ nodes,
                                              const float* __restrict__ ent,
                                              bf16* __restrict__ gA) {
    int g = blockIdx.x;                 // b*512+np
    int b = g >> 9, np = g & 511;
    int nbase = (((b << 10) + 512 + np) << 3);
    size_t rbase = (size_t)g * 8;
    int tid = threadIdx.x;
    for (int it = 0; it < 6; it++) {
        int chunk = it * 256 + tid;     // [0,1536): 8 rows * 192 float4-chunks
        int m = chunk / 192, piece = chunk % 192;
        int id = nodes[nbase + m];
        const float4* s = (const float4*)(ent + (size_t)id * 768) + piece;
        float4 v = *s;
        union { bf16 h[4]; uint2 u; } pk;
        pk.h[0] = f2b(v.x); pk.h[1] = f2b(v.y); pk.h[2] = f2b(v.z); pk.h[3] = f2b(v.w);
        *(uint2*)(gA + (rbase + m) * 768 + piece * 4) = pk.u;
    }
}

// --------------------------------------------------------------- MFMA GEMM
// C[M,N] = A[M,K] @ Bt[N,K]^T.  EPIL: 0=bf16, 1=bias+relu->bf16, 2=bias->bf16,
// 3=f32, 4=bias + h-remap f32 (N==256)
template <int EPIL>
__global__ __launch_bounds__(256) void gemm_bt(const bf16* __restrict__ A,
                                               const bf16* __restrict__ Bt,
                                               bf16* __restrict__ Cb, float* __restrict__ Cf,
                                               const float* __restrict__ bias,
                                               int M, int N, int K, int NT) {
    __shared__ bf16 As[128][32];
    __shared__ bf16 Bs[128][32];
    const int tid = threadIdx.x;
    const int m0 = (blockIdx.x / NT) * 128;
    const int n0 = (blockIdx.x % NT) * 128;
    const int lane = tid & 63;
    const int wave = tid >> 6;
    const int wm = (wave >> 1) << 6;
    const int wn = (wave & 1) << 6;
    const int rsel = lane & 15;
    const int qd = lane >> 4;
    f32x4 acc[4][4];
#pragma unroll
    for (int i = 0; i < 4; i++)
#pragma unroll
        for (int j = 0; j < 4; j++) acc[i][j] = (f32x4){0.f, 0.f, 0.f, 0.f};

    const int c0 = tid, r0 = c0 >> 2, kk0 = (c0 & 3) << 3;
    const int c1 = tid + 256, r1 = c1 >> 2, kk1 = (c1 & 3) << 3;

    for (int k0 = 0; k0 < K; k0 += 32) {
        __syncthreads();
        {
            const bf16* ga0 = A + (size_t)(m0 + r0) * K + (k0 + kk0);
            __builtin_amdgcn_global_load_lds((gbl_u32*)ga0, (lds_u32*)&As[r0][kk0], 16, 0, 0);
            const bf16* ga1 = A + (size_t)(m0 + r1) * K + (k0 + kk1);
            __builtin_amdgcn_global_load_lds((gbl_u32*)ga1, (lds_u32*)&As[r1][kk1], 16, 0, 0);
            const bf16* gb0 = Bt + (size_t)(n0 + r0) * K + (k0 + kk0);
            __builtin_amdgcn_global_load_lds((gbl_u32*)gb0, (lds_u32*)&Bs[r0][kk0], 16, 0, 0);
            const bf16* gb1 = Bt + (size_t)(n0 + r1) * K + (k0 + kk1);
            __builtin_amdgcn_global_load_lds((gbl_u32*)gb1, (lds_u32*)&Bs[r1][kk1], 16, 0, 0);
        }
        __syncthreads();
        short8 af[4], bfr[4];
#pragma unroll
        for (int i = 0; i < 4; i++) af[i] = *(const short8*)&As[wm + i * 16 + rsel][qd << 3];
#pragma unroll
        for (int j = 0; j < 4; j++) bfr[j] = *(const short8*)&Bs[wn + j * 16 + rsel][qd << 3];
#pragma unroll
        for (int i = 0; i < 4; i++)
#pragma unroll
            for (int j = 0; j < 4; j++)
                acc[i][j] = __builtin_amdgcn_mfma_f32_16x16x32_bf16(af[i], bfr[j], acc[i][j], 0, 0, 0);
    }
#pragma unroll
    for (int i = 0; i < 4; i++) {
        const int rbase = m0 + wm + i * 16 + (qd << 2);
#pragma unroll
        for (int j = 0; j < 4; j++) {
            const int col = n0 + wn + j * 16 + rsel;
            float bv = 0.f;
            if constexpr (EPIL == 1 || EPIL == 2 || EPIL == 4) bv = bias[col];
#pragma unroll
            for (int r = 0; r < 4; r++) {
                const int row = rbase + r;
                float v = acc[i][j][r] + bv;
                if constexpr (EPIL == 1) v = fmaxf(v, 0.f);
                if constexpr (EPIL == 0 || EPIL == 1 || EPIL == 2) {
                    Cb[(size_t)row * N + col] = f2b(v);
                } else if constexpr (EPIL == 3) {
                    Cf[(size_t)row * N + col] = v;
                } else {
                    const int bb = row >> 10, nn2 = row & 1023;
                    Cf[((size_t)bb * HSTRIDE + 1 + nn2) * 256 + col] = v;
                }
            }
        }
    }
}

// ----------------------------------------------------------------- pooling
// pooled[b*1024+n][d] = sum_m nm * (n<512 ? entity_row(f32) : mlp_out row(bf16))
__global__ __launch_bounds__(256) void k_pool(const int* __restrict__ nodes,
                                              const float* __restrict__ nmask,
                                              const float* __restrict__ ent,
                                              const bf16* __restrict__ mlp_out,
                                              bf16* __restrict__ pooled) {
    int bid = blockIdx.x;  // b*1024+n
    int b = bid >> 10, n = bid & 1023;
    int tid = threadIdx.x;
    float a0 = 0.f, a1 = 0.f, a2 = 0.f;
    int base = bid * 8;
    if (n < 512) {
        for (int m = 0; m < 8; m++) {
            float w = nmask[base + m];
            const float* row = ent + (size_t)nodes[base + m] * 768;
            a0 += w * row[tid];
            a1 += w * row[tid + 256];
            a2 += w * row[tid + 512];
        }
    } else {
        for (int m = 0; m < 8; m++) {
            float w = nmask[base + m];
            const bf16* row = mlp_out + ((size_t)((b * 512 + (n - 512)) * 8 + m)) * 768;
            a0 += w * b2f(row[tid]);
            a1 += w * b2f(row[tid + 256]);
            a2 += w * b2f(row[tid + 512]);
        }
    }
    bf16* dst = pooled + (size_t)bid * 768;
    dst[tid] = f2b(a0);
    dst[tid + 256] = f2b(a1);
    dst[tid + 512] = f2b(a2);
}

// ------------------------------------------------------------- h row 0 (tv)
__global__ __launch_bounds__(256) void k_h0(const float* __restrict__ tv,
                                            const float* __restrict__ proj_w,
                                            const float* __restrict__ proj_b,
                                            float* __restrict__ h) {
    int b = blockIdx.x, c = threadIdx.x;
    float acc = proj_b[c];
    for (int k = 0; k < 768; k++) acc += tv[b * 768 + k] * proj_w[k * 256 + c];
    h[((size_t)b * HSTRIDE) * 256 + c] = acc;
}

// ------------------------------------------- type-embed add + hbf + padding
__global__ __launch_bounds__(256) void k_tpe_add(const int* __restrict__ ntypes,
                                                 const float* __restrict__ tpe,
                                                 float* __restrict__ h, bf16* __restrict__ hbf) {
    int i = blockIdx.x;  // 0..1039
    int b = blockIdx.y;
    int c = threadIdx.x;
    size_t idx = ((size_t)b * HSTRIDE + i) * 256 + c;
    if (i < NNODES) {
        int t = ntypes[b * NNODES + i];
        float v = h[idx] + tpe[t * 256 + c];
        h[idx] = v;
        hbf[idx] = f2b(v);
    } else {
        h[idx] = 0.f;
        hbf[idx] = f2b(0.f);
    }
}

// ----------------------------------------------------------------- CSR build
__global__ void k_zero(int* p, int n) {
    int i = blockIdx.x * 256 + threadIdx.x;
    if (i < n) p[i] = 0;
}

__global__ __launch_bounds__(256) void k_count(const int* __restrict__ edges,
                                               int* __restrict__ counts) {
    int flat = blockIdx.x * 256 + threadIdx.x;  // b*EE + e
    int b = flat >> 14, e = flat & (EE - 1);
    int d = edges[b * 2 * EE + EE + e];
    atomicAdd(&counts[b * NNODES + d], 1);
}

__global__ __launch_bounds__(256) void k_scan(const int* __restrict__ counts,
                                              int* __restrict__ offs, int* __restrict__ cursor) {
    int b = blockIdx.x, t = threadIdx.x;
    __shared__ int tsum[256];
    int beg = t * 5;
    int end = beg + 5;
    if (end > NNODES) end = NNODES;
    int cl[5];
    int s = 0;
    for (int i = beg; i < end; i++) {
        int v = counts[b * NNODES + i];
        cl[i - beg] = v;
        s += v;
    }
    tsum[t] = s;
    __syncthreads();
    for (int d = 1; d < 256; d <<= 1) {
        int v = tsum[t];
        int vo = (t >= d) ? tsum[t - d] : 0;
        __syncthreads();
        tsum[t] = v + vo;
        __syncthreads();
    }
    int run = (t == 0) ? 0 : tsum[t - 1];
    for (int i = beg; i < end; i++) {
        offs[b * 1026 + i] = run;
        cursor[b * NNODES + i] = run;
        run += cl[i - beg];
    }
    if (beg == NNODES) offs[b * 1026 + NNODES] = run;
}

__global__ __launch_bounds__(256) void k_scatter(const int* __restrict__ edges,
                                                 int* __restrict__ cursor, int* __restrict__ eord) {
    int flat = blockIdx.x * 256 + threadIdx.x;
    int b = flat >> 14, e = flat & (EE - 1);
    int d = edges[b * 2 * EE + EE + e];
    int pos = atomicAdd(&cursor[b * NNODES + d], 1);
    eord[b * EE + pos] = e;
}

// ------------------------------------------------ GNN attention per dst node
__global__ __launch_bounds__(256) void k_gnn_node(const int* __restrict__ edges,
                                                  const int* __restrict__ etypes,
                                                  const int* __restrict__ offs,
                                                  const int* __restrict__ eord,
                                                  const float* __restrict__ etewe,
                                                  const float* __restrict__ qkv,
                                                  float* __restrict__ h, bf16* __restrict__ hbf) {
    int bid = blockIdx.x;
    int b = bid / NNODES, n = bid % NNODES;
    int o0 = offs[b * 1026 + n];
    int deg = offs[b * 1026 + n + 1] - o0;
    if (deg > MAXDEG) deg = MAXDEG;
    int tid = threadIdx.x, lane = tid & 63, wave = tid >> 6;
    __shared__ float qs[256];
    __shared__ float elog[MAXDEG][4];
    __shared__ int srcs[MAXDEG];
    __shared__ float smax[4], sden[4];
    size_t qbase = ((size_t)(b * HSTRIDE + n)) * 768;
    qs[tid] = qkv[qbase + tid];
    __syncthreads();
    for (int i = wave; i < deg; i += 4) {
        int e = eord[b * EE + o0 + i];
        int src = edges[b * 2 * EE + e];
        int et = etypes[b * EE + e];
        const float* krow = qkv + ((size_t)(b * HSTRIDE + src)) * 768 + 256;
        const float* kerow = etewe + et * 256;
        float sum[4];
#pragma unroll
        for (int hh = 0; hh < 4; hh++) {
            float v = qs[hh * 64 + lane] * (krow[hh * 64 + lane] + kerow[hh * 64 + lane]);
            for (int s = 32; s > 0; s >>= 1) v += __shfl_xor(v, s, 64);
            sum[hh] = v;
        }
        if (lane == 0) {
            srcs[i] = src;
#pragma unroll
            for (int hh = 0; hh < 4; hh++) elog[i][hh] = sum[hh] * 0.125f;
        }
    }
    __syncthreads();
    if (tid < 4 && deg > 0) {
        float m = -1e30f;
        for (int i = 0; i < deg; i++) m = fmaxf(m, elog[i][tid]);
        float den = 0.f;
        for (int i = 0; i < deg; i++) den += expf(elog[i][tid] - m);
        smax[tid] = m;
        sden[tid] = den;
    }
    __syncthreads();
    for (int i = tid; i < deg; i += 256) {
#pragma unroll
        for (int hh = 0; hh < 4; hh++)
            elog[i][hh] = expf(elog[i][hh] - smax[hh]) / (sden[hh] + 1e-9f);
    }
    __syncthreads();
    int head = tid >> 6;
    float acc = 0.f;
    for (int i = 0; i < deg; i++)
        acc += elog[i][head] * qkv[((size_t)(b * HSTRIDE + srcs[i])) * 768 + 512 + tid];
    size_t hidx = ((size_t)(b * HSTRIDE + n)) * 256 + tid;
    float v = h[hidx] + acc;
    v = fmaxf(v, 0.f);
    h[hidx] = v;
    hbf[hidx] = f2b(v);
}

// ----------------------------------------------------------------- classifier
__global__ __launch_bounds__(256) void k_cls(const float* __restrict__ h,
                                             const float* __restrict__ tv,
                                             const float* __restrict__ weff,
                                             const float* __restrict__ beff,
                                             float* __restrict__ out) {
    int bc = blockIdx.x;
    int b = bc / 50, c = bc % 50;
    int tid = threadIdx.x;
    const float* we = weff + c * 1280;
    float acc = 0.f;
    for (int kk = tid; kk < 1280; kk += 256) {
        float f;
        if (kk < 256) f = h[((size_t)(b * HSTRIDE)) * 256 + kk];
        else if (kk < 512) f = h[((size_t)(b * HSTRIDE + 1 + c)) * 256 + (kk - 256)];
        else f = tv[b * 768 + (kk - 512)];
        acc += f * we[kk];
    }
    __shared__ float red[256];
    red[tid] = acc;
    __syncthreads();
    for (int s = 128; s > 0; s >>= 1) {
        if (tid < s) red[tid] += red[tid + s];
        __syncthreads();
    }
    if (tid == 0) out[b * 50 + c] = red[0] + beff[c];
}

// ======================================================================
extern "C" void kernel_launch(void* const* d_in, const int* in_sizes, int n_in,
                              void* d_out, int out_size, void* d_ws, size_t ws_size,
                              hipStream_t stream) {
    (void)in_sizes; (void)n_in; (void)out_size; (void)ws_size;
    const int* sentence       = (const int*)d_in[0];
    const float* mask         = (const float*)d_in[1];
    const int* nodes          = (const int*)d_in[2];
    const float* node_mask    = (const float*)d_in[3];
    const int* node_types     = (const int*)d_in[4];
    const int* edges          = (const int*)d_in[5];
    const int* edge_types     = (const int*)d_in[6];
    const float* word_embed   = (const float*)d_in[7];
    const float* entity_table = (const float*)d_in[8];
    const float* type_table   = (const float*)d_in[9];
    const float* mlp_w1       = (const float*)d_in[10];
    const float* mlp_b1       = (const float*)d_in[11];
    const float* mlp_w2       = (const float*)d_in[12];
    const float* mlp_b2       = (const float*)d_in[13];
    const float* ntw_w        = (const float*)d_in[14];
    const float* proj_w       = (const float*)d_in[15];
    const float* proj_b       = (const float*)d_in[16];
    const float* type_proj_w  = (const float*)d_in[17];
    const float* edge_tt      = (const float*)d_in[18];
    const float* gnn_wq       = (const float*)d_in[19];
    const float* gnn_wk       = (const float*)d_in[20];
    const float* gnn_wv       = (const float*)d_in[21];
    const float* gnn_we       = (const float*)d_in[22];
    const float* cls_w        = (const float*)d_in[23];
    const float* cls_b        = (const float*)d_in[24];
    const float* cls2_w       = (const float*)d_in[25];
    const float* cls2_b       = (const float*)d_in[26];

    char* ws = (char*)d_ws;
    size_t off = 0;
    auto alloc = [&](size_t bytes) {
        size_t r = off;
        off += (bytes + 255) & ~((size_t)255);
        return r;
    };
    bf16* w1t    = (bf16*)(ws + alloc((size_t)1024 * 768 * 2));
    bf16* w2t    = (bf16*)(ws + alloc((size_t)768 * 1024 * 2));
    bf16* ntwt   = (bf16*)(ws + alloc((size_t)768 * 768 * 2));
    bf16* projt  = (bf16*)(ws + alloc((size_t)256 * 768 * 2));
    bf16* wqkvt  = (bf16*)(ws + alloc((size_t)2 * 768 * 256 * 2));
    float* tpe   = (float*)(ws + alloc((size_t)100 * 256 * 4));
    float* etewe = (float*)(ws + alloc((size_t)2 * 50 * 256 * 4));
    float* weff  = (float*)(ws + alloc((size_t)50 * 1280 * 4));
    float* beff  = (float*)(ws + alloc(256));
    float* tv    = (float*)(ws + alloc((size_t)8 * 768 * 4));
    int* counts  = (int*)(ws + alloc((size_t)8 * NNODES * 4));
    int* offs    = (int*)(ws + alloc((size_t)8 * 1026 * 4));
    int* cursor  = (int*)(ws + alloc((size_t)8 * NNODES * 4));
    int* eord    = (int*)(ws + alloc((size_t)8 * EE * 4));
    bf16* gathA  = (bf16*)(ws + alloc((size_t)32768 * 768 * 2));  // also mlp_out
    char* region = ws + alloc((size_t)67108864);                   // overlay region
    bf16* hidden = (bf16*)region;                                  // [32768][1024]
    bf16* pooled = (bf16*)(region + 0);                            // after hidden dead
    bf16* ne2    = (bf16*)(region + 12582912);
    float* h     = (float*)(region + 25165824);                    // [8][1040][256]
    bf16* hbf    = (bf16*)(region + 33685504);
    float* qkv   = (float*)(region + 37945344);                    // [8][1040][768]
    bf16* mlp_out = gathA;

    dim3 tb(32, 8);
    // weight transposes (f32 -> bf16)
    k_transpose_cvt<<<dim3(32, 24), tb, 0, stream>>>(mlp_w1, w1t, 768, 1024);
    k_transpose_cvt<<<dim3(24, 32), tb, 0, stream>>>(mlp_w2, w2t, 1024, 768);
    k_transpose_cvt<<<dim3(24, 24), tb, 0, stream>>>(ntw_w, ntwt, 768, 768);
    k_transpose_cvt<<<dim3(8, 24), tb, 0, stream>>>(proj_w, projt, 768, 256);
    for (int l = 0; l < 2; l++) {
        k_transpose_cvt<<<dim3(8, 8), tb, 0, stream>>>(gnn_wq + l * 65536, wqkvt + l * 196608, 256, 256);
        k_transpose_cvt<<<dim3(8, 8), tb, 0, stream>>>(gnn_wk + l * 65536, wqkvt + l * 196608 + 65536, 256, 256);
        k_transpose_cvt<<<dim3(8, 8), tb, 0, stream>>>(gnn_wv + l * 65536, wqkvt + l * 196608 + 131072, 256, 256);
    }
    // small precomputes
    k_small_mm<<<100, 256, 0, stream>>>(type_table, type_proj_w, tpe, 50);
    k_small_mm<<<50, 256, 0, stream>>>(edge_tt, gnn_we, etewe, 50);
    k_small_mm<<<50, 256, 0, stream>>>(edge_tt, gnn_we + 12800, etewe + 12800, 50);
    k_weff<<<dim3(320, 50), 256, 0, stream>>>(cls_w, cls2_w, weff);
    k_beff<<<50, 64, 0, stream>>>(cls_b, cls2_b, cls2_w, beff);
    k_textvec<<<8, 256, 0, stream>>>(sentence, mask, word_embed, tv);

    // MLP over logic nodes
    k_gath<<<4096, 256, 0, stream>>>(nodes, entity_table, gathA);
    gemm_bt<1><<<2048, 256, 0, stream>>>(gathA, w1t, hidden, nullptr, mlp_b1, 32768, 1024, 768, 8);
    gemm_bt<2><<<1536, 256, 0, stream>>>(hidden, w2t, mlp_out, nullptr, mlp_b2, 32768, 768, 1024, 6);
    // masked pool (kg: gather f32, logic: mlp_out bf16) -> pooled (ntw after pool)
    k_pool<<<8192, 256, 0, stream>>>(nodes, node_mask, entity_table, mlp_out, pooled);
    gemm_bt<0><<<384, 256, 0, stream>>>(pooled, ntwt, ne2, nullptr, nullptr, 8192, 768, 768, 6);
    gemm_bt<4><<<128, 256, 0, stream>>>(ne2, projt, nullptr, h, proj_b, 8192, 256, 768, 2);
    k_h0<<<8, 256, 0, stream>>>(tv, proj_w, proj_b, h);
    k_tpe_add<<<dim3(1040, 8), 256, 0, stream>>>(node_types, tpe, h, hbf);

    // CSR by dst (shared by both layers)
    k_zero<<<(8 * NNODES + 255) / 256, 256, 0, stream>>>(counts, 8 * NNODES);
    k_count<<<512, 256, 0, stream>>>(edges, counts);
    k_scan<<<8, 256, 0, stream>>>(counts, offs, cursor);
    k_scatter<<<512, 256, 0, stream>>>(edges, cursor, eord);

    for (int l = 0; l < 2; l++) {
        gemm_bt<3><<<390, 256, 0, stream>>>(hbf, wqkvt + l * 196608, nullptr, qkv, nullptr, 8320, 768, 256, 6);
        k_gnn_node<<<8 * NNODES, 256, 0, stream>>>(edges, edge_types, offs, eord,
                                                   etewe + l * 12800, qkv, h, hbf);
    }
    k_cls<<<400, 256, 0, stream>>>(h, tv, weff, beff, (float*)d_out);
}

// Round 3
// 945.629 us; speedup vs baseline: 1.1200x; 1.1200x over previous
//
#include <hip/hip_runtime.h>
#include <hip/hip_bf16.h>
#include <stdint.h>

using bf16 = __hip_bfloat16;
typedef __attribute__((ext_vector_type(8))) short short8;
typedef __attribute__((ext_vector_type(4))) float f32x4;
typedef __attribute__((address_space(3))) unsigned int lds_u32;
typedef const __attribute__((address_space(1))) unsigned int gbl_u32;

#define HSTRIDE 1040
#define NNODES 1025
#define EE 16384
#define MAXDEG 192

__device__ __forceinline__ bf16 f2b(float x) { return __float2bfloat16(x); }
__device__ __forceinline__ float b2f(bf16 x) { return __bfloat162float(x); }

// mask index for logic row: row=(b*512+np)*8+m -> node_mask[(b*1024+512+np)*8+m]
__device__ __forceinline__ size_t midx(int row) {
    int G = row >> 3, m = row & 7, b = G >> 9;
    return (size_t)(G + 512 * (b + 1)) * 8 + m;
}

// ------------------------------------------- transpose f32 -> bf16 [C][R]
__global__ __launch_bounds__(256) void k_transpose_cvt(const float* __restrict__ in,
                                                       bf16* __restrict__ out, int R, int C) {
    __shared__ float tile[32][33];
    int bx = blockIdx.x * 32;
    int by = blockIdx.y * 32;
    int tx = threadIdx.x, ty = threadIdx.y;  // (32,8)
    for (int i = 0; i < 32; i += 8)
        tile[ty + i][tx] = in[(size_t)(by + ty + i) * C + bx + tx];
    __syncthreads();
    for (int i = 0; i < 32; i += 8)
        out[(size_t)(bx + ty + i) * R + by + tx] = f2b(tile[tx][ty + i]);
}

// ------------------------------------------------- small GEMM (N fixed 256)
__global__ __launch_bounds__(256) void k_small_mm(const float* __restrict__ X,
                                                  const float* __restrict__ W,
                                                  float* __restrict__ out, int Kdim) {
    int r = blockIdx.x, c = threadIdx.x;
    float acc = 0.f;
    for (int k = 0; k < Kdim; k++) acc += X[r * Kdim + k] * W[k * 256 + c];
    out[r * 256 + c] = acc;
}

// ---------------------------------------------------- classifier weight fold
__global__ __launch_bounds__(256) void k_weff(const float* __restrict__ cls_w,
                                              const float* __restrict__ cls2_w,
                                              float* __restrict__ weff) {
    int c = blockIdx.y;
    int wave = threadIdx.x >> 6, lane = threadIdx.x & 63;
    int k = blockIdx.x * 4 + wave;
    float acc = 0.f;
    for (int e = lane; e < 768; e += 64)
        acc += cls_w[(size_t)k * 768 + e] * cls2_w[c * 768 + e];
    for (int s = 32; s > 0; s >>= 1) acc += __shfl_xor(acc, s, 64);
    if (lane == 0) weff[c * 1280 + k] = acc;
}

__global__ __launch_bounds__(64) void k_beff(const float* __restrict__ cls_b,
                                             const float* __restrict__ cls2_b,
                                             const float* __restrict__ cls2_w,
                                             float* __restrict__ beff) {
    int c = blockIdx.x, lane = threadIdx.x;
    float acc = 0.f;
    for (int e = lane; e < 768; e += 64) acc += cls_b[e] * cls2_w[c * 768 + e];
    for (int s = 32; s > 0; s >>= 1) acc += __shfl_xor(acc, s, 64);
    if (lane == 0) beff[c] = acc + cls2_b[c];
}

// ------------------------------------------------ text_vec: partials + reduce
__global__ __launch_bounds__(256) void k_textvec_part(const int* __restrict__ sent,
                                                      const float* __restrict__ mask,
                                                      const float* __restrict__ we,
                                                      float* __restrict__ tvp,
                                                      float* __restrict__ msump) {
    int b = blockIdx.x, ch = blockIdx.y, tid = threadIdx.x;
    float a0 = 0.f, a1 = 0.f, a2 = 0.f, ms = 0.f;
    for (int l = ch * 32; l < ch * 32 + 32; l++) {
        int w = sent[b * 256 + l];
        float mm = mask[b * 256 + l];
        const float* row = we + (size_t)w * 768;
        a0 += mm * row[tid];
        a1 += mm * row[tid + 256];
        a2 += mm * row[tid + 512];
        ms += mm;
    }
    float* dst = tvp + (size_t)(b * 8 + ch) * 768;
    dst[tid] = a0;
    dst[tid + 256] = a1;
    dst[tid + 512] = a2;
    if (tid == 0) msump[b * 8 + ch] = ms;
}

__global__ __launch_bounds__(256) void k_tvred(const float* __restrict__ tvp,
                                               const float* __restrict__ msump,
                                               float* __restrict__ tv) {
    int b = blockIdx.x, tid = threadIdx.x;
    float ms = 0.f;
    for (int p = 0; p < 8; p++) ms += msump[b * 8 + p];
    float inv = 1.f / (ms + 1e-9f);
    float a0 = 0.f, a1 = 0.f, a2 = 0.f;
    for (int p = 0; p < 8; p++) {
        const float* s = tvp + (size_t)(b * 8 + p) * 768;
        a0 += s[tid];
        a1 += s[tid + 256];
        a2 += s[tid + 512];
    }
    tv[b * 768 + tid] = a0 * inv;
    tv[b * 768 + tid + 256] = a1 * inv;
    tv[b * 768 + tid + 512] = a2 * inv;
}

// -------------- gemm1 fused: gather-A entity rows, relu+bias, mask-pool out
// out: pooledh[G][n] = sum_m w(G,m)*relu( ent_row @ w1t^T + b1 )
__global__ __launch_bounds__(256) void gemm_mlp1(const int* __restrict__ nodes,
                                                 const float* __restrict__ ent,
                                                 const bf16* __restrict__ Bt,
                                                 const float* __restrict__ b1,
                                                 const float* __restrict__ node_mask,
                                                 bf16* __restrict__ pooledh) {
    __shared__ bf16 As[128][32];
    __shared__ bf16 Bs[128][32];
    const int tid = threadIdx.x;
    const int m0 = (blockIdx.x >> 3) * 128;
    const int n0 = (blockIdx.x & 7) * 128;
    const int lane = tid & 63;
    const int wave = tid >> 6;
    const int wm = (wave >> 1) << 6;
    const int wn = (wave & 1) << 6;
    const int rsel = lane & 15;
    const int qd = lane >> 4;
    const int K = 768;

    // per-thread A gather pointers (4 passes of 32 rows)
    const float* arow[4];
    int rl_row = tid >> 3;           // 0..31
    int piece4 = (tid & 7) << 2;     // elem offset 0..28
#pragma unroll
    for (int p = 0; p < 4; p++) {
        int grow = m0 + p * 32 + rl_row;
        int id = nodes[midx(grow)];
        arow[p] = ent + (size_t)id * 768 + piece4;
    }

    f32x4 acc[4][4];
#pragma unroll
    for (int i = 0; i < 4; i++)
#pragma unroll
        for (int j = 0; j < 4; j++) acc[i][j] = (f32x4){0.f, 0.f, 0.f, 0.f};

    const int c0 = tid, r0 = c0 >> 2, kk0 = (c0 & 3) << 3;
    const int c1 = tid + 256, r1 = c1 >> 2, kk1 = (c1 & 3) << 3;

    for (int k0 = 0; k0 < K; k0 += 32) {
        __syncthreads();
        // B: async direct-to-LDS
        const bf16* gb0 = Bt + (size_t)(n0 + r0) * K + (k0 + kk0);
        __builtin_amdgcn_global_load_lds((gbl_u32*)gb0, (lds_u32*)&Bs[r0][kk0], 16, 0, 0);
        const bf16* gb1 = Bt + (size_t)(n0 + r1) * K + (k0 + kk1);
        __builtin_amdgcn_global_load_lds((gbl_u32*)gb1, (lds_u32*)&Bs[r1][kk1], 16, 0, 0);
        // A: gathered f32 -> bf16 via regs
#pragma unroll
        for (int p = 0; p < 4; p++) {
            float4 v = *(const float4*)(arow[p] + k0);
            union { bf16 h[4]; uint2 u; } pk;
            pk.h[0] = f2b(v.x); pk.h[1] = f2b(v.y); pk.h[2] = f2b(v.z); pk.h[3] = f2b(v.w);
            *(uint2*)&As[p * 32 + rl_row][piece4] = pk.u;
        }
        __syncthreads();
        short8 af[4], bfr[4];
#pragma unroll
        for (int i = 0; i < 4; i++) af[i] = *(const short8*)&As[wm + i * 16 + rsel][qd << 3];
#pragma unroll
        for (int j = 0; j < 4; j++) bfr[j] = *(const short8*)&Bs[wn + j * 16 + rsel][qd << 3];
#pragma unroll
        for (int i = 0; i < 4; i++)
#pragma unroll
            for (int j = 0; j < 4; j++)
                acc[i][j] = __builtin_amdgcn_mfma_f32_16x16x32_bf16(af[i], bfr[j], acc[i][j], 0, 0, 0);
    }
    // epilogue: relu + bias, masked pool over 8-row groups
#pragma unroll
    for (int i = 0; i < 4; i++) {
        const int rbase = m0 + wm + i * 16 + (qd << 2);
        float w4[4];
#pragma unroll
        for (int r = 0; r < 4; r++) w4[r] = node_mask[midx(rbase + r)];
        const int Gout = (m0 + wm + i * 16 + ((qd & 2) << 2)) >> 3;
#pragma unroll
        for (int j = 0; j < 4; j++) {
            const int col = n0 + wn + j * 16 + rsel;
            const float bv = b1[col];
            float s = 0.f;
#pragma unroll
            for (int r = 0; r < 4; r++) s += w4[r] * fmaxf(acc[i][j][r] + bv, 0.f);
            s += __shfl_xor(s, 16, 64);
            if ((qd & 1) == 0) pooledh[(size_t)Gout * 1024 + col] = f2b(s);
        }
    }
}

// summask[G] = sum_m node_mask over logic group G
__global__ __launch_bounds__(256) void k_summask(const float* __restrict__ node_mask,
                                                 float* __restrict__ summask) {
    int G = blockIdx.x * 256 + threadIdx.x;
    if (G >= 4096) return;
    int b = G >> 9;
    const float* p = node_mask + (size_t)(G + 512 * (b + 1)) * 8;
    float s = 0.f;
    for (int m = 0; m < 8; m++) s += p[m];
    summask[G] = s;
}

// --------------------------------------------------------------- MFMA GEMM
// C = A @ Bt^T.  EPIL: 0=bf16 plain, 3=f32 plain, 4=bias + h-remap f32,
// 5=rowscale*bias -> bf16, remapped to pooled logic rows
template <int EPIL>
__global__ __launch_bounds__(256) void gemm_bt(const bf16* __restrict__ A,
                                               const bf16* __restrict__ Bt,
                                               bf16* __restrict__ Cb, float* __restrict__ Cf,
                                               const float* __restrict__ bias,
                                               const float* __restrict__ smr,
                                               int M, int N, int K, int NT) {
    __shared__ bf16 As[128][32];
    __shared__ bf16 Bs[128][32];
    const int tid = threadIdx.x;
    const int m0 = (blockIdx.x / NT) * 128;
    const int n0 = (blockIdx.x % NT) * 128;
    const int lane = tid & 63;
    const int wave = tid >> 6;
    const int wm = (wave >> 1) << 6;
    const int wn = (wave & 1) << 6;
    const int rsel = lane & 15;
    const int qd = lane >> 4;
    f32x4 acc[4][4];
#pragma unroll
    for (int i = 0; i < 4; i++)
#pragma unroll
        for (int j = 0; j < 4; j++) acc[i][j] = (f32x4){0.f, 0.f, 0.f, 0.f};

    const int c0 = tid, r0 = c0 >> 2, kk0 = (c0 & 3) << 3;
    const int c1 = tid + 256, r1 = c1 >> 2, kk1 = (c1 & 3) << 3;

    for (int k0 = 0; k0 < K; k0 += 32) {
        __syncthreads();
        {
            const bf16* ga0 = A + (size_t)(m0 + r0) * K + (k0 + kk0);
            __builtin_amdgcn_global_load_lds((gbl_u32*)ga0, (lds_u32*)&As[r0][kk0], 16, 0, 0);
            const bf16* ga1 = A + (size_t)(m0 + r1) * K + (k0 + kk1);
            __builtin_amdgcn_global_load_lds((gbl_u32*)ga1, (lds_u32*)&As[r1][kk1], 16, 0, 0);
            const bf16* gb0 = Bt + (size_t)(n0 + r0) * K + (k0 + kk0);
            __builtin_amdgcn_global_load_lds((gbl_u32*)gb0, (lds_u32*)&Bs[r0][kk0], 16, 0, 0);
            const bf16* gb1 = Bt + (size_t)(n0 + r1) * K + (k0 + kk1);
            __builtin_amdgcn_global_load_lds((gbl_u32*)gb1, (lds_u32*)&Bs[r1][kk1], 16, 0, 0);
        }
        __syncthreads();
        short8 af[4], bfr[4];
#pragma unroll
        for (int i = 0; i < 4; i++) af[i] = *(const short8*)&As[wm + i * 16 + rsel][qd << 3];
#pragma unroll
        for (int j = 0; j < 4; j++) bfr[j] = *(const short8*)&Bs[wn + j * 16 + rsel][qd << 3];
#pragma unroll
        for (int i = 0; i < 4; i++)
#pragma unroll
            for (int j = 0; j < 4; j++)
                acc[i][j] = __builtin_amdgcn_mfma_f32_16x16x32_bf16(af[i], bfr[j], acc[i][j], 0, 0, 0);
    }
#pragma unroll
    for (int i = 0; i < 4; i++) {
        const int rbase = m0 + wm + i * 16 + (qd << 2);
        float sm4[4];
        if constexpr (EPIL == 5) {
#pragma unroll
            for (int r = 0; r < 4; r++) sm4[r] = smr[rbase + r];
        }
#pragma unroll
        for (int j = 0; j < 4; j++) {
            const int col = n0 + wn + j * 16 + rsel;
            float bv = 0.f;
            if constexpr (EPIL == 4 || EPIL == 5) bv = bias[col];
#pragma unroll
            for (int r = 0; r < 4; r++) {
                const int row = rbase + r;
                if constexpr (EPIL == 0) {
                    Cb[(size_t)row * N + col] = f2b(acc[i][j][r]);
                } else if constexpr (EPIL == 3) {
                    Cf[(size_t)row * N + col] = acc[i][j][r];
                } else if constexpr (EPIL == 4) {
                    const int bb = row >> 10, nn2 = row & 1023;
                    Cf[((size_t)bb * HSTRIDE + 1 + nn2) * 256 + col] = acc[i][j][r] + bv;
                } else {  // 5: gemm2 -> pooled logic rows
                    const int dest = row + 512 * ((row >> 9) + 1);
                    Cb[(size_t)dest * N + col] = f2b(acc[i][j][r] + sm4[r] * bv);
                }
            }
        }
    }
}

// --------------------------------------------------- kg pooling (n < 512)
__global__ __launch_bounds__(256) void k_pool_kg(const int* __restrict__ nodes,
                                                 const float* __restrict__ nmask,
                                                 const float* __restrict__ ent,
                                                 bf16* __restrict__ pooled) {
    int bid = blockIdx.x;  // b*512+n
    int b = bid >> 9, n = bid & 511;
    int tid = threadIdx.x;
    int base = (((b << 10) + n) << 3);
    float a0 = 0.f, a1 = 0.f, a2 = 0.f;
    for (int m = 0; m < 8; m++) {
        float w = nmask[base + m];
        const float* row = ent + (size_t)nodes[base + m] * 768;
        a0 += w * row[tid];
        a1 += w * row[tid + 256];
        a2 += w * row[tid + 512];
    }
    bf16* dst = pooled + (size_t)((b << 10) + n) * 768;
    dst[tid] = f2b(a0);
    dst[tid + 256] = f2b(a1);
    dst[tid + 512] = f2b(a2);
}

// --------------------------------------------- h row0 partials (tv @ proj_w)
__global__ __launch_bounds__(256) void k_h0p(const float* __restrict__ tv,
                                             const float* __restrict__ proj_w,
                                             float* __restrict__ hp) {
    int b = blockIdx.x, kc = blockIdx.y, c = threadIdx.x;
    float acc = 0.f;
    for (int k = kc * 128; k < kc * 128 + 128; k++)
        acc += tv[b * 768 + k] * proj_w[k * 256 + c];
    hp[(size_t)(b * 6 + kc) * 256 + c] = acc;
}

// --------------------- type-embed add + h row0 assembly + hbf + zero padding
__global__ __launch_bounds__(256) void k_tpe_add(const int* __restrict__ ntypes,
                                                 const float* __restrict__ tpe,
                                                 const float* __restrict__ hp,
                                                 const float* __restrict__ proj_b,
                                                 float* __restrict__ h, bf16* __restrict__ hbf) {
    int i = blockIdx.x;  // 0..1039
    int b = blockIdx.y;
    int c = threadIdx.x;
    size_t idx = ((size_t)b * HSTRIDE + i) * 256 + c;
    if (i < NNODES) {
        int t = ntypes[b * NNODES + i];
        float v;
        if (i == 0) {
            v = proj_b[c];
            for (int p = 0; p < 6; p++) v += hp[(size_t)(b * 6 + p) * 256 + c];
        } else {
            v = h[idx];
        }
        v += tpe[t * 256 + c];
        h[idx] = v;
        hbf[idx] = f2b(v);
    } else {
        h[idx] = 0.f;
        hbf[idx] = f2b(0.f);
    }
}

// ----------------------------------------------------------------- CSR build
__global__ void k_zero(int* p, int n) {
    int i = blockIdx.x * 256 + threadIdx.x;
    if (i < n) p[i] = 0;
}

__global__ __launch_bounds__(256) void k_count(const int* __restrict__ edges,
                                               int* __restrict__ counts) {
    int flat = blockIdx.x * 256 + threadIdx.x;
    int b = flat >> 14, e = flat & (EE - 1);
    int d = edges[b * 2 * EE + EE + e];
    atomicAdd(&counts[b * NNODES + d], 1);
}

__global__ __launch_bounds__(256) void k_scan(const int* __restrict__ counts,
                                              int* __restrict__ offs, int* __restrict__ cursor) {
    int b = blockIdx.x, t = threadIdx.x;
    __shared__ int tsum[256];
    int beg = t * 5;
    int end = beg + 5;
    if (end > NNODES) end = NNODES;
    int cl[5];
    int s = 0;
    for (int i = beg; i < end; i++) {
        int v = counts[b * NNODES + i];
        cl[i - beg] = v;
        s += v;
    }
    tsum[t] = s;
    __syncthreads();
    for (int d = 1; d < 256; d <<= 1) {
        int v = tsum[t];
        int vo = (t >= d) ? tsum[t - d] : 0;
        __syncthreads();
        tsum[t] = v + vo;
        __syncthreads();
    }
    int run = (t == 0) ? 0 : tsum[t - 1];
    for (int i = beg; i < end; i++) {
        offs[b * 1026 + i] = run;
        cursor[b * NNODES + i] = run;
        run += cl[i - beg];
    }
    if (beg == NNODES) offs[b * 1026 + NNODES] = run;
}

__global__ __launch_bounds__(256) void k_scatter(const int* __restrict__ edges,
                                                 int* __restrict__ cursor, int* __restrict__ eord) {
    int flat = blockIdx.x * 256 + threadIdx.x;
    int b = flat >> 14, e = flat & (EE - 1);
    int d = edges[b * 2 * EE + EE + e];
    int pos = atomicAdd(&cursor[b * NNODES + d], 1);
    eord[b * EE + pos] = e;
}

// ------------------------------------------------ GNN attention per dst node
__global__ __launch_bounds__(256) void k_gnn_node(const int* __restrict__ edges,
                                                  const int* __restrict__ etypes,
                                                  const int* __restrict__ offs,
                                                  const int* __restrict__ eord,
                                                  const float* __restrict__ etewe,
                                                  const float* __restrict__ qkv,
                                                  float* __restrict__ h, bf16* __restrict__ hbf) {
    int bid = blockIdx.x;
    int b = bid / NNODES, n = bid % NNODES;
    int o0 = offs[b * 1026 + n];
    int deg = offs[b * 1026 + n + 1] - o0;
    if (deg > MAXDEG) deg = MAXDEG;
    int tid = threadIdx.x, lane = tid & 63, wave = tid >> 6;
    __shared__ float qs[256];
    __shared__ float elog[MAXDEG][4];
    __shared__ int srcs[MAXDEG];
    __shared__ float smax[4], sden[4];
    size_t qbase = ((size_t)(b * HSTRIDE + n)) * 768;
    qs[tid] = qkv[qbase + tid];
    __syncthreads();
    for (int i = wave; i < deg; i += 4) {
        int e = eord[b * EE + o0 + i];
        int src = edges[b * 2 * EE + e];
        int et = etypes[b * EE + e];
        const float* krow = qkv + ((size_t)(b * HSTRIDE + src)) * 768 + 256;
        const float* kerow = etewe + et * 256;
        float sum[4];
#pragma unroll
        for (int hh = 0; hh < 4; hh++) {
            float v = qs[hh * 64 + lane] * (krow[hh * 64 + lane] + kerow[hh * 64 + lane]);
            for (int s = 32; s > 0; s >>= 1) v += __shfl_xor(v, s, 64);
            sum[hh] = v;
        }
        if (lane == 0) {
            srcs[i] = src;
#pragma unroll
            for (int hh = 0; hh < 4; hh++) elog[i][hh] = sum[hh] * 0.125f;
        }
    }
    __syncthreads();
    if (tid < 4 && deg > 0) {
        float m = -1e30f;
        for (int i = 0; i < deg; i++) m = fmaxf(m, elog[i][tid]);
        float den = 0.f;
        for (int i = 0; i < deg; i++) den += expf(elog[i][tid] - m);
        smax[tid] = m;
        sden[tid] = den;
    }
    __syncthreads();
    for (int i = tid; i < deg; i += 256) {
#pragma unroll
        for (int hh = 0; hh < 4; hh++)
            elog[i][hh] = expf(elog[i][hh] - smax[hh]) / (sden[hh] + 1e-9f);
    }
    __syncthreads();
    int head = tid >> 6;
    float acc = 0.f;
    for (int i = 0; i < deg; i++)
        acc += elog[i][head] * qkv[((size_t)(b * HSTRIDE + srcs[i])) * 768 + 512 + tid];
    size_t hidx = ((size_t)(b * HSTRIDE + n)) * 256 + tid;
    float v = h[hidx] + acc;
    v = fmaxf(v, 0.f);
    h[hidx] = v;
    hbf[hidx] = f2b(v);
}

// ----------------------------------------------------------------- classifier
__global__ __launch_bounds__(256) void k_cls(const float* __restrict__ h,
                                             const float* __restrict__ tv,
                                             const float* __restrict__ weff,
                                             const float* __restrict__ beff,
                                             float* __restrict__ out) {
    int bc = blockIdx.x;
    int b = bc / 50, c = bc % 50;
    int tid = threadIdx.x;
    const float* we = weff + c * 1280;
    float acc = 0.f;
    for (int kk = tid; kk < 1280; kk += 256) {
        float f;
        if (kk < 256) f = h[((size_t)(b * HSTRIDE)) * 256 + kk];
        else if (kk < 512) f = h[((size_t)(b * HSTRIDE + 1 + c)) * 256 + (kk - 256)];
        else f = tv[b * 768 + (kk - 512)];
        acc += f * we[kk];
    }
    __shared__ float red[256];
    red[tid] = acc;
    __syncthreads();
    for (int s = 128; s > 0; s >>= 1) {
        if (tid < s) red[tid] += red[tid + s];
        __syncthreads();
    }
    if (tid == 0) out[b * 50 + c] = red[0] + beff[c];
}

// ======================================================================
extern "C" void kernel_launch(void* const* d_in, const int* in_sizes, int n_in,
                              void* d_out, int out_size, void* d_ws, size_t ws_size,
                              hipStream_t stream) {
    (void)in_sizes; (void)n_in; (void)out_size; (void)ws_size;
    const int* sentence       = (const int*)d_in[0];
    const float* mask         = (const float*)d_in[1];
    const int* nodes          = (const int*)d_in[2];
    const float* node_mask    = (const float*)d_in[3];
    const int* node_types     = (const int*)d_in[4];
    const int* edges          = (const int*)d_in[5];
    const int* edge_types     = (const int*)d_in[6];
    const float* word_embed   = (const float*)d_in[7];
    const float* entity_table = (const float*)d_in[8];
    const float* type_table   = (const float*)d_in[9];
    const float* mlp_w1       = (const float*)d_in[10];
    const float* mlp_b1       = (const float*)d_in[11];
    const float* mlp_w2       = (const float*)d_in[12];
    const float* mlp_b2       = (const float*)d_in[13];
    const float* ntw_w        = (const float*)d_in[14];
    const float* proj_w       = (const float*)d_in[15];
    const float* proj_b       = (const float*)d_in[16];
    const float* type_proj_w  = (const float*)d_in[17];
    const float* edge_tt      = (const float*)d_in[18];
    const float* gnn_wq       = (const float*)d_in[19];
    const float* gnn_wk       = (const float*)d_in[20];
    const float* gnn_wv       = (const float*)d_in[21];
    const float* gnn_we       = (const float*)d_in[22];
    const float* cls_w        = (const float*)d_in[23];
    const float* cls_b        = (const float*)d_in[24];
    const float* cls2_w       = (const float*)d_in[25];
    const float* cls2_b       = (const float*)d_in[26];

    char* ws = (char*)d_ws;
    size_t off = 0;
    auto alloc = [&](size_t bytes) {
        size_t r = off;
        off += (bytes + 255) & ~((size_t)255);
        return r;
    };
    bf16* w1t     = (bf16*)(ws + alloc((size_t)1024 * 768 * 2));
    bf16* w2t     = (bf16*)(ws + alloc((size_t)768 * 1024 * 2));
    bf16* ntwt    = (bf16*)(ws + alloc((size_t)768 * 768 * 2));
    bf16* projt   = (bf16*)(ws + alloc((size_t)256 * 768 * 2));
    bf16* wqkvt   = (bf16*)(ws + alloc((size_t)2 * 768 * 256 * 2));
    float* tpe    = (float*)(ws + alloc((size_t)100 * 256 * 4));
    float* etewe  = (float*)(ws + alloc((size_t)2 * 50 * 256 * 4));
    float* weff   = (float*)(ws + alloc((size_t)50 * 1280 * 4));
    float* beff   = (float*)(ws + alloc(256));
    float* tv     = (float*)(ws + alloc((size_t)8 * 768 * 4));
    float* tvp    = (float*)(ws + alloc((size_t)64 * 768 * 4));
    float* msump  = (float*)(ws + alloc((size_t)64 * 4));
    float* hp     = (float*)(ws + alloc((size_t)48 * 256 * 4));
    float* summask= (float*)(ws + alloc((size_t)4096 * 4));
    int* counts   = (int*)(ws + alloc((size_t)8 * NNODES * 4));
    int* offs     = (int*)(ws + alloc((size_t)8 * 1026 * 4));
    int* cursor   = (int*)(ws + alloc((size_t)8 * NNODES * 4));
    int* eord     = (int*)(ws + alloc((size_t)8 * EE * 4));
    bf16* pooledh = (bf16*)(ws + alloc((size_t)4096 * 1024 * 2));
    bf16* pooled  = (bf16*)(ws + alloc((size_t)8192 * 768 * 2));
    bf16* ne2     = (bf16*)(ws + alloc((size_t)8192 * 768 * 2));
    float* h      = (float*)(ws + alloc((size_t)8 * HSTRIDE * 256 * 4));
    bf16* hbf     = (bf16*)(ws + alloc((size_t)8 * HSTRIDE * 256 * 2));
    float* qkv    = (float*)(ws + alloc((size_t)8 * HSTRIDE * 768 * 4));

    dim3 tb(32, 8);
    // weight transposes (f32 -> bf16)
    k_transpose_cvt<<<dim3(32, 24), tb, 0, stream>>>(mlp_w1, w1t, 768, 1024);
    k_transpose_cvt<<<dim3(24, 32), tb, 0, stream>>>(mlp_w2, w2t, 1024, 768);
    k_transpose_cvt<<<dim3(24, 24), tb, 0, stream>>>(ntw_w, ntwt, 768, 768);
    k_transpose_cvt<<<dim3(8, 24), tb, 0, stream>>>(proj_w, projt, 768, 256);
    for (int l = 0; l < 2; l++) {
        k_transpose_cvt<<<dim3(8, 8), tb, 0, stream>>>(gnn_wq + l * 65536, wqkvt + l * 196608, 256, 256);
        k_transpose_cvt<<<dim3(8, 8), tb, 0, stream>>>(gnn_wk + l * 65536, wqkvt + l * 196608 + 65536, 256, 256);
        k_transpose_cvt<<<dim3(8, 8), tb, 0, stream>>>(gnn_wv + l * 65536, wqkvt + l * 196608 + 131072, 256, 256);
    }
    // small precomputes
    k_small_mm<<<100, 256, 0, stream>>>(type_table, type_proj_w, tpe, 50);
    k_small_mm<<<50, 256, 0, stream>>>(edge_tt, gnn_we, etewe, 50);
    k_small_mm<<<50, 256, 0, stream>>>(edge_tt, gnn_we + 12800, etewe + 12800, 50);
    k_weff<<<dim3(320, 50), 256, 0, stream>>>(cls_w, cls2_w, weff);
    k_beff<<<50, 64, 0, stream>>>(cls_b, cls2_b, cls2_w, beff);
    k_textvec_part<<<dim3(8, 8), 256, 0, stream>>>(sentence, mask, word_embed, tvp, msump);
    k_tvred<<<8, 256, 0, stream>>>(tvp, msump, tv);

    // MLP over logic nodes: fused gather + GEMM1 + relu + mask-pool
    gemm_mlp1<<<2048, 256, 0, stream>>>(nodes, entity_table, w1t, mlp_b1, node_mask, pooledh);
    k_summask<<<16, 256, 0, stream>>>(node_mask, summask);
    // GEMM2 on pooled hidden (M=4096), epilogue scatters into pooled logic rows
    gemm_bt<5><<<192, 256, 0, stream>>>(pooledh, w2t, pooled, nullptr, mlp_b2, summask, 4096, 768, 1024, 6);
    // kg pooling
    k_pool_kg<<<4096, 256, 0, stream>>>(nodes, node_mask, entity_table, pooled);
    // ntw + proj
    gemm_bt<0><<<384, 256, 0, stream>>>(pooled, ntwt, ne2, nullptr, nullptr, nullptr, 8192, 768, 768, 6);
    gemm_bt<4><<<128, 256, 0, stream>>>(ne2, projt, nullptr, h, proj_b, nullptr, 8192, 256, 768, 2);
    k_h0p<<<dim3(8, 6), 256, 0, stream>>>(tv, proj_w, hp);
    k_tpe_add<<<dim3(1040, 8), 256, 0, stream>>>(node_types, tpe, hp, proj_b, h, hbf);

    // CSR by dst (shared by both layers)
    k_zero<<<(8 * NNODES + 255) / 256, 256, 0, stream>>>(counts, 8 * NNODES);
    k_count<<<512, 256, 0, stream>>>(edges, counts);
    k_scan<<<8, 256, 0, stream>>>(counts, offs, cursor);
    k_scatter<<<512, 256, 0, stream>>>(edges, cursor, eord);

    for (int l = 0; l < 2; l++) {
        gemm_bt<3><<<390, 256, 0, stream>>>(hbf, wqkvt + l * 196608, nullptr, qkv, nullptr, nullptr, 8320, 768, 256, 6);
        k_gnn_node<<<8 * NNODES, 256, 0, stream>>>(edges, edge_types, offs, eord,
                                                   etewe + l * 12800, qkv, h, hbf);
    }
    k_cls<<<400, 256, 0, stream>>>(h, tv, weff, beff, (float*)d_out);
}